// Round 15
// baseline (341.796 us; speedup 1.0000x reference)
//
#include <hip/hip_runtime.h>

#define NE    512
#define DIM   64
#define NROWS 131072            // 32*64*64
#define QELEMS (NROWS * DIM)    // 8388608

// ---- output layout (flat f32, reference return order) ----
#define OFF_Q     0
#define OFF_LOSS  8388608
#define OFF_INDS  8388609
#define OFF_NEMB  8519681       // OFF_INDS + 131072
#define OFF_NCS   8552449       // OFF_NEMB + 32768
#define OFF_NEA   8552961       // OFF_NCS  + 512

// ---- workspace layout (float-unit offsets; some regions int/ushort) ----
#define WS_EMBT    0            // [512][64] f32 transposed codebook (e-major)
#define WS_ENORM   32768        // [512] f32 ||e||^2
#define WS_ESUM    33280        // [512][64] f32 segment sums (atomic flush)
#define WS_COUNTSF 66048        // [512] f32 counts
#define WS_LOSS    66560        // [1] f32
#define WS_FRAG    66564        // [4 quarters][hi 8192 | lo 8192] ushort of -2e
#define WS_CAND    99332        // [131072][4] f32: half0 top-2 | half1 top-2
#define WS_INDS    623620       // [131072] int row -> code
#define WS_SORT    754692       // [131072] int sorted row ids
#define WS_HIST    885764       // [512] int per-code totals
#define WS_START   886276       // [512] int bucket starts
#define WS_HIST2   886788       // [512 codes][512 blocks] int partials (transposed)

typedef __attribute__((ext_vector_type(8))) short short8;
typedef __attribute__((ext_vector_type(4))) float float4v;

__device__ inline unsigned short bf16_rne(float v) {
    unsigned u = __float_as_uint(v);
    u += 0x7fff + ((u >> 16) & 1);
    return (unsigned short)(u >> 16);
}

// insert candidate p into ascending best-2 (b0<=b1): 2 VALU ops
#define INS2(p, b0, b1)                              \
    do {                                             \
        float _p = (p);                              \
        b1 = __builtin_amdgcn_fmed3f(_p, b0, b1);    \
        b0 = fminf(_p, b0);                          \
    } while (0)

// ---------------------------------------------------------------------------
// init: embT + enorm, zero esum/counts/loss, build quarter-major bf16 frags
// of -2*e (so MFMA accumulates the distance directly). grid = 517 x 256.
__global__ __launch_bounds__(256) void k_init(const float* __restrict__ embed,
                                              float* __restrict__ wsf) {
    int tid = blockIdx.x * 256 + threadIdx.x;
    if (tid < 32768) {
        int e = tid >> 6, d = tid & 63;
        wsf[WS_EMBT + tid] = embed[d * NE + e];          // embT[e][d]
    } else if (tid < 33280) {
        int e = tid - 32768;
        float s = 0.f;
        for (int d = 0; d < DIM; ++d) {
            float v = embed[d * NE + e];
            s = fmaf(v, v, s);
        }
        wsf[WS_ENORM + e] = s;
    } else if (tid < 66561) {
        wsf[tid] = 0.f;                                  // ESUM + COUNTSF + LOSS
    } else if (tid >= 66564 && tid < 66564 + 65536) {
        // frag entry ft: q=quarter, part=hi/lo, s=[t8][kt][l][j]; value -2e
        int ft = tid - 66564;
        int q  = ft >> 14;
        int part = (ft >> 13) & 1;
        int s  = ft & 8191;
        int j  = s & 7;
        int l  = (s >> 3) & 63;
        int kt = (s >> 9) & 1;
        int t8 = s >> 10;                                // 0..7
        int k  = kt * 32 + 8 * (l >> 4) + j;
        int n  = q * 128 + t8 * 16 + (l & 15);
        float v = -2.0f * embed[k * NE + n];
        unsigned short hi = bf16_rne(v);
        unsigned short o;
        if (part == 0) o = hi;
        else {
            float fhi = __uint_as_float((unsigned)hi << 16);
            o = bf16_rne(v - fhi);
        }
        ((unsigned short*)(wsf + WS_FRAG))[ft] = o;
    }
}

// ---------------------------------------------------------------------------
// k_scan: CODE-HALF SPLIT. Each block: 256 rows x 256 codes (2 quarters).
// grid 1024 (bid>>1 = row block, bid&1 = code half), 512 thr, 34KB LDS ->
// 4 blocks/CU = 32 waves/CU if VGPR<=64 (launch_bounds(512,8); no manual
// prefetch regs, #pragma unroll t-loop). Distance folded into MFMA.
__global__ __launch_bounds__(512, 8) void k_scan(const float* __restrict__ in,
                                                 const float* __restrict__ wsf,
                                                 float* __restrict__ cand) {
    extern __shared__ char smem[];
    short* lhi = (short*)smem;                 // 8192 shorts (hi of -2e)
    short* llo = lhi + 8192;                   // 8192 shorts (lo of -2e)
    float* len = (float*)(lhi + 16384);        // 512 f32

    const int w = threadIdx.x >> 6, l = threadIdx.x & 63;
    const int g = l >> 4, c = l & 15;
    const int half = blockIdx.x & 1;
    const int rowbase = (blockIdx.x >> 1) * 256 + w * 32;

    // A fragments: rows (l&15), k-slots 8g..8g+7 per ktile, split hi/lo
    short8 ahi[2][2], alo[2][2];
#pragma unroll
    for (int mt = 0; mt < 2; ++mt) {
        const float* xr = in + (size_t)(rowbase + mt * 16 + c) * DIM;
#pragma unroll
        for (int kt = 0; kt < 2; ++kt) {
            float4v x0 = *(const float4v*)(xr + kt * 32 + 8 * g);
            float4v x1 = *(const float4v*)(xr + kt * 32 + 8 * g + 4);
            float a[8] = {x0[0], x0[1], x0[2], x0[3], x1[0], x1[1], x1[2], x1[3]};
            short8 h, lo8;
#pragma unroll
            for (int j = 0; j < 8; ++j) {
                unsigned short hb = bf16_rne(a[j]);
                float fhi = __uint_as_float((unsigned)hb << 16);
                h[j]   = (short)hb;
                lo8[j] = (short)bf16_rne(a[j] - fhi);
            }
            ahi[mt][kt] = h;
            alo[mt][kt] = lo8;
        }
    }

    float bst[2][4][2];
#pragma unroll
    for (int mt = 0; mt < 2; ++mt)
#pragma unroll
        for (int j = 0; j < 4; ++j) {
            bst[mt][j][0] = 3.4e38f; bst[mt][j][1] = 3.4e38f;
        }

    for (int qq = 0; qq < 2; ++qq) {
        const int q = half * 2 + qq;           // global quarter
        __syncthreads();                       // prior quarter's reads done
        const int4* src = (const int4*)(wsf + WS_FRAG) + q * 2048;
        int4* dst = (int4*)lhi;
#pragma unroll
        for (int i = 0; i < 4; ++i) dst[i * 512 + threadIdx.x] = src[i * 512 + threadIdx.x];
        if (qq == 0) len[threadIdx.x] = wsf[WS_ENORM + threadIdx.x];
        __syncthreads();

        // this quarter's 8 ||e||^2 values for my code column c
        float en_r[8];
#pragma unroll
        for (int t = 0; t < 8; ++t) en_r[t] = len[q * 128 + t * 16 + c];

#pragma unroll
        for (int t = 0; t < 8; ++t) {
            short8 bh0 = *(const short8*)(lhi + (t * 2 + 0) * 512 + l * 8);
            short8 bh1 = *(const short8*)(lhi + (t * 2 + 1) * 512 + l * 8);
            short8 bl0 = *(const short8*)(llo + (t * 2 + 0) * 512 + l * 8);
            short8 bl1 = *(const short8*)(llo + (t * 2 + 1) * 512 + l * 8);
            float en = en_r[t];
            float4v acc0 = {en, en, en, en};   // d = ||e||^2 - 2 x.e via MFMA
            float4v acc1 = {en, en, en, en};
            acc0 = __builtin_amdgcn_mfma_f32_16x16x32_bf16(ahi[0][0], bh0, acc0, 0, 0, 0);
            acc1 = __builtin_amdgcn_mfma_f32_16x16x32_bf16(ahi[1][0], bh0, acc1, 0, 0, 0);
            acc0 = __builtin_amdgcn_mfma_f32_16x16x32_bf16(ahi[0][1], bh1, acc0, 0, 0, 0);
            acc1 = __builtin_amdgcn_mfma_f32_16x16x32_bf16(ahi[1][1], bh1, acc1, 0, 0, 0);
            acc0 = __builtin_amdgcn_mfma_f32_16x16x32_bf16(alo[0][0], bh0, acc0, 0, 0, 0);
            acc1 = __builtin_amdgcn_mfma_f32_16x16x32_bf16(alo[1][0], bh0, acc1, 0, 0, 0);
            acc0 = __builtin_amdgcn_mfma_f32_16x16x32_bf16(alo[0][1], bh1, acc0, 0, 0, 0);
            acc1 = __builtin_amdgcn_mfma_f32_16x16x32_bf16(alo[1][1], bh1, acc1, 0, 0, 0);
            acc0 = __builtin_amdgcn_mfma_f32_16x16x32_bf16(ahi[0][0], bl0, acc0, 0, 0, 0);
            acc1 = __builtin_amdgcn_mfma_f32_16x16x32_bf16(ahi[1][0], bl0, acc1, 0, 0, 0);
            acc0 = __builtin_amdgcn_mfma_f32_16x16x32_bf16(ahi[0][1], bl1, acc0, 0, 0, 0);
            acc1 = __builtin_amdgcn_mfma_f32_16x16x32_bf16(ahi[1][1], bl1, acc1, 0, 0, 0);

            unsigned nn = (unsigned)(q * 128 + t * 16 + c) & 0x1FFu;
#pragma unroll
            for (int j = 0; j < 4; ++j) {
                float p0 = __uint_as_float((__float_as_uint(acc0[j]) & 0xFFFFFE00u) | nn);
                INS2(p0, bst[0][j][0], bst[0][j][1]);
                float p1 = __uint_as_float((__float_as_uint(acc1[j]) & 0xFFFFFE00u) | nn);
                INS2(p1, bst[1][j][0], bst[1][j][1]);
            }
        }
    }

    // in-wave merge over the 16 c-lanes; lane c==0 stores its half's 8B pair
#pragma unroll
    for (int mt = 0; mt < 2; ++mt)
#pragma unroll
        for (int j = 0; j < 4; ++j) {
            float c0 = bst[mt][j][0], c1 = bst[mt][j][1];
#pragma unroll
            for (int m = 1; m < 16; m <<= 1) {
                float o0 = __shfl_xor(c0, m, 64);
                float o1 = __shfl_xor(c1, m, 64);
                INS2(o0, c0, c1);
                INS2(o1, c0, c1);
            }
            if (c == 0) {
                int row = rowbase + mt * 16 + 4 * g + j;
                float2 cd; cd.x = c0; cd.y = c1;
                *(float2*)(cand + (size_t)row * 4 + 2 * half) = cd;
            }
        }
}

// ---------------------------------------------------------------------------
// k_rerank: FOUR threads per row (sub = t&3). Merge the two halves' packed
// top-2 (order-exact min/med), fp64 re-rank of 2, Q write, loss, inds, hist.
__global__ __launch_bounds__(1024, 8) void k_rerank(const float* __restrict__ in,
                                                    float* __restrict__ wsf,
                                                    int* __restrict__ wsi,
                                                    float* __restrict__ inds_out,
                                                    float* __restrict__ qout) {
    __shared__ int lh[512];
    __shared__ float lred[16];
    int b = blockIdx.x, t = threadIdx.x;
    if (t < 512) lh[t] = 0;
    __syncthreads();

    int row = b * 256 + (t >> 2);
    int sub = t & 3;
    float4v cd4 = *(const float4v*)(wsf + WS_CAND + (size_t)row * 4);
    // top-2 of union of two sorted pairs (a0<=a1, b0<=b1)
    float a0 = cd4[0], a1 = cd4[1], b0 = cd4[2], b1 = cd4[3];
    float m0 = fminf(a0, b0);
    float m1 = fminf(fmaxf(a0, b0), fminf(a1, b1));
    int i0 = (int)(__float_as_uint(m0) & 0x1FFu);
    int i1 = (int)(__float_as_uint(m1) & 0x1FFu);

    const float4v* in4 = (const float4v*)in;
    const float4v* em4 = (const float4v*)(wsf + WS_EMBT);
    double s0 = 0.0, s1 = 0.0, xn = 0.0;
#pragma unroll 2
    for (int q4 = 0; q4 < 4; ++q4) {
        int idx = q4 * 4 + sub;                // wave insn covers full 64B lines
        float4v xv = in4[(size_t)row * 16 + idx];
        float4v e0 = em4[i0 * 16 + idx];
        float4v e1 = em4[i1 * 16 + idx];
#pragma unroll
        for (int q = 0; q < 4; ++q) {
            double xd = (double)xv[q];
            double a = (double)e0[q]; s0 += a * (a - 2.0 * xd);
            double bb = (double)e1[q]; s1 += bb * (bb - 2.0 * xd);
            xn += xd * xd;
        }
    }
#pragma unroll
    for (int m = 1; m < 4; m <<= 1) {
        s0 += __shfl_xor(s0, m, 64);
        s1 += __shfl_xor(s1, m, 64);
        xn += __shfl_xor(xn, m, 64);
    }
    double sb = s0; int ib = i0;
    if (s1 < sb || (s1 == sb && i1 < ib)) { sb = s1; ib = i1; }

    const float4v* eb = em4 + ib * 16;
    float4v* qp = (float4v*)qout + (size_t)row * 16;
#pragma unroll 2
    for (int q4 = 0; q4 < 4; ++q4) {
        int idx = q4 * 4 + sub;
        qp[idx] = eb[idx];
    }

    float ls = 0.f;
    if (sub == 0) {
        inds_out[row] = (float)ib;
        wsi[WS_INDS + row] = ib;
        atomicAdd(&lh[ib], 1);
        ls = (float)(sb + xn);                 // ||q-x||^2
    }
    for (int off = 32; off; off >>= 1) ls += __shfl_down(ls, off, 64);
    if ((t & 63) == 0) lred[t >> 6] = ls;
    __syncthreads();
    if (t == 0) {
        float s = 0.f;
        for (int i = 0; i < 16; ++i) s += lred[i];
        atomicAdd(&wsf[WS_LOSS], s);
    }
    // hist -> HIST2T[code][block] (transposed: scan1 reads coalesced)
    if (t < 512) wsi[WS_HIST2 + t * 512 + b] = lh[t];
}

// ---------------------------------------------------------------------------
// scan1: per-code exclusive scan over 512 block-partials (coalesced reads);
// totals -> HIST/COUNTSF. grid = 512 codes.
__global__ __launch_bounds__(512) void k_scan1(int* __restrict__ wsi,
                                               float* __restrict__ wsf) {
    __shared__ int s[512];
    int e = blockIdx.x, p = threadIdx.x;
    int v = wsi[WS_HIST2 + e * 512 + p];
    s[p] = v;
    __syncthreads();
    for (int off = 1; off < 512; off <<= 1) {
        int a = (p >= off) ? s[p - off] : 0;
        __syncthreads();
        s[p] += a;
        __syncthreads();
    }
    wsi[WS_HIST2 + e * 512 + p] = s[p] - v;
    if (p == 511) {
        wsi[WS_HIST + e] = s[511];
        wsf[WS_COUNTSF + e] = (float)s[511];
    }
}

// ---------------------------------------------------------------------------
// scan2: exclusive scan of per-code totals -> bucket starts. 1 block.
__global__ __launch_bounds__(512) void k_scan2(int* __restrict__ wsi) {
    __shared__ int s[NE];
    int t = threadIdx.x;
    int v = wsi[WS_HIST + t];
    s[t] = v;
    __syncthreads();
    for (int off = 1; off < NE; off <<= 1) {
        int a = (t >= off) ? s[t - off] : 0;
        __syncthreads();
        s[t] += a;
        __syncthreads();
    }
    wsi[WS_START + t] = s[t] - v;
}

// ---------------------------------------------------------------------------
// scatter: atomic-free globally; LDS local rank + scanned (code,block) offset.
__global__ __launch_bounds__(256) void k_scatter(int* __restrict__ wsi) {
    __shared__ int lc[NE];
    int b = blockIdx.x, t = threadIdx.x;
    lc[t] = 0; lc[t + 256] = 0;
    __syncthreads();
    int row = b * 256 + t;
    int ind = wsi[WS_INDS + row];
    int lr = atomicAdd(&lc[ind], 1);
    int pos = wsi[WS_START + ind] + wsi[WS_HIST2 + ind * 512 + b] + lr;
    wsi[WS_SORT + pos] = row;
}

// ---------------------------------------------------------------------------
// sum: skew-immune; wave owns 32 contiguous sorted positions, shfl broadcast,
// flush on (wave-uniform) code change. grid = 1024 x 256.
__global__ __launch_bounds__(256) void k_sum(const float* __restrict__ in,
                                             const int* __restrict__ wsi,
                                             float* __restrict__ wsf) {
    float* __restrict__ esum = wsf + WS_ESUM;
    int wv = threadIdx.x >> 6, lane = threadIdx.x & 63;
    int base = (blockIdx.x * 4 + wv) * 32;
    int rid = 0, cod = 0;
    if (lane < 32) {
        rid = wsi[WS_SORT + base + lane];
        cod = wsi[WS_INDS + rid];
    }
    float acc = 0.f;
    int cur = __shfl(cod, 0, 64);
#pragma unroll 8
    for (int j = 0; j < 32; ++j) {
        int cj = __shfl(cod, j, 64);
        int rj = __shfl(rid, j, 64);
        if (cj != cur) {
            atomicAdd(&esum[cur * DIM + lane], acc);
            acc = 0.f;
            cur = cj;
        }
        acc += in[(size_t)rj * DIM + lane];
    }
    atomicAdd(&esum[cur * DIM + lane], acc);
}

// ---------------------------------------------------------------------------
// finalize: EMA buffers + normalized codebook + loss scale. One block.
__global__ __launch_bounds__(512) void k_final(const float* __restrict__ wsf,
                                               const float* __restrict__ cs_in,
                                               const float* __restrict__ eavg_in,
                                               float* __restrict__ out) {
    __shared__ float sred[512];
    int t = threadIdx.x;
    float c = 0.99f * cs_in[t] + 0.01f * wsf[WS_COUNTSF + t];
    out[OFF_NCS + t] = c;
    sred[t] = c;
    __syncthreads();
    for (int s = 256; s; s >>= 1) {
        if (t < s) sred[t] += sred[t + s];
        __syncthreads();
    }
    float n = sred[0];
    float csv = (c + 1e-5f) / (n + NE * 1e-5f) * n;
    for (int i = t; i < 32768; i += 512) {               // i & 511 == t, d = i>>9
        float nea = 0.99f * eavg_in[i] + 0.01f * wsf[WS_ESUM + t * DIM + (i >> 9)];
        out[OFF_NEA + i]  = nea;
        out[OFF_NEMB + i] = nea / csv;
    }
    if (t == 0) out[OFF_LOSS] = wsf[WS_LOSS] * (1.25f / 8388608.0f);
}

// ---------------------------------------------------------------------------
extern "C" void kernel_launch(void* const* d_in, const int* in_sizes, int n_in,
                              void* d_out, int out_size, void* d_ws, size_t ws_size,
                              hipStream_t stream) {
    const float* in    = (const float*)d_in[0];
    const float* embed = (const float*)d_in[1];
    const float* cs    = (const float*)d_in[2];
    const float* eavg  = (const float*)d_in[3];
    float* out = (float*)d_out;
    float* wsf = (float*)d_ws;
    int*   wsi = (int*)d_ws;

    k_init   <<<517, 256, 0, stream>>>(embed, wsf);
    k_scan   <<<1024, 512, 34816, stream>>>(in, wsf, wsf + WS_CAND);
    k_rerank <<<512, 1024, 0, stream>>>(in, wsf, wsi, out + OFF_INDS, out + OFF_Q);
    k_scan1  <<<NE, 512, 0, stream>>>(wsi, wsf);
    k_scan2  <<<1, 512, 0, stream>>>(wsi);
    k_scatter<<<512, 256, 0, stream>>>(wsi);
    k_sum    <<<1024, 256, 0, stream>>>(in, wsi, wsf);
    k_final  <<<1, 512, 0, stream>>>(wsf, cs, eavg, out);
}

// Round 16
// 112.440 us; speedup vs baseline: 3.0398x; 3.0398x over previous
//
#include <hip/hip_runtime.h>

#define NE    512
#define DIM   64
#define NROWS 131072            // 32*64*64
#define QELEMS (NROWS * DIM)    // 8388608

// ---- output layout (flat f32, reference return order) ----
#define OFF_Q     0
#define OFF_LOSS  8388608
#define OFF_INDS  8388609
#define OFF_NEMB  8519681       // OFF_INDS + 131072
#define OFF_NCS   8552449       // OFF_NEMB + 32768
#define OFF_NEA   8552961       // OFF_NCS  + 512

// ---- workspace layout (float-unit offsets; some regions int/ushort) ----
#define WS_EMBT    0            // [512][64] f32 transposed codebook (e-major)
#define WS_ENORM   32768        // [512] f32 ||e||^2
#define WS_ESUM    33280        // [512][64] f32 segment sums (atomic flush)
#define WS_COUNTSF 66048        // [512] f32 counts
#define WS_LOSS    66560        // [1] f32
#define WS_FRAG    66564        // [4 quarters][hi 8192 | lo 8192] ushort of -2e
#define WS_CAND    99332        // [131072][4] f32: half0 top-2 | half1 top-2
#define WS_INDS    623620       // [131072] int row -> code
#define WS_SORT    754692       // [131072] int sorted row ids
#define WS_HIST    885764       // [512] int per-code totals
#define WS_START   886276       // [512] int bucket starts
#define WS_HIST2   886788       // [512 codes][512 blocks] int partials (transposed)

typedef __attribute__((ext_vector_type(8))) short short8;
typedef __attribute__((ext_vector_type(4))) float float4v;

__device__ inline unsigned short bf16_rne(float v) {
    unsigned u = __float_as_uint(v);
    u += 0x7fff + ((u >> 16) & 1);
    return (unsigned short)(u >> 16);
}

// insert candidate p into ascending best-2 (b0<=b1): 2 VALU ops
#define INS2(p, b0, b1)                              \
    do {                                             \
        float _p = (p);                              \
        b1 = __builtin_amdgcn_fmed3f(_p, b0, b1);    \
        b0 = fminf(_p, b0);                          \
    } while (0)

// ---------------------------------------------------------------------------
// init: embT + enorm, zero esum/counts/loss, build quarter-major bf16 frags
// of -2*e (so MFMA accumulates the distance directly). grid = 517 x 256.
__global__ __launch_bounds__(256) void k_init(const float* __restrict__ embed,
                                              float* __restrict__ wsf) {
    int tid = blockIdx.x * 256 + threadIdx.x;
    if (tid < 32768) {
        int e = tid >> 6, d = tid & 63;
        wsf[WS_EMBT + tid] = embed[d * NE + e];          // embT[e][d]
    } else if (tid < 33280) {
        int e = tid - 32768;
        float s = 0.f;
        for (int d = 0; d < DIM; ++d) {
            float v = embed[d * NE + e];
            s = fmaf(v, v, s);
        }
        wsf[WS_ENORM + e] = s;
    } else if (tid < 66561) {
        wsf[tid] = 0.f;                                  // ESUM + COUNTSF + LOSS
    } else if (tid >= 66564 && tid < 66564 + 65536) {
        // frag entry ft: q=quarter, part=hi/lo, s=[t8][kt][l][j]; value -2e
        int ft = tid - 66564;
        int q  = ft >> 14;
        int part = (ft >> 13) & 1;
        int s  = ft & 8191;
        int j  = s & 7;
        int l  = (s >> 3) & 63;
        int kt = (s >> 9) & 1;
        int t8 = s >> 10;                                // 0..7
        int k  = kt * 32 + 8 * (l >> 4) + j;
        int n  = q * 128 + t8 * 16 + (l & 15);
        float v = -2.0f * embed[k * NE + n];
        unsigned short hi = bf16_rne(v);
        unsigned short o;
        if (part == 0) o = hi;
        else {
            float fhi = __uint_as_float((unsigned)hi << 16);
            o = bf16_rne(v - fhi);
        }
        ((unsigned short*)(wsf + WS_FRAG))[ft] = o;
    }
}

// ---------------------------------------------------------------------------
// k_scan: CODE-HALF SPLIT, R12 register regime. Each block: 256 rows x 256
// codes (2 quarters). grid 1024 (bid>>1 = row block, bid&1 = code half),
// 512 thr, 34KB LDS -> 4 blocks/CU = 32 waves/CU at VGPR<=64.
// launch_bounds(512,2): the bound that compiled to 64 VGPR / no spill in
// R12-R14 (R15's (512,8) forced VGPR=32 -> 490MB spill).
__global__ __launch_bounds__(512, 2) void k_scan(const float* __restrict__ in,
                                                 const float* __restrict__ wsf,
                                                 float* __restrict__ cand) {
    extern __shared__ char smem[];
    short* lhi = (short*)smem;                 // 8192 shorts (hi of -2e)
    short* llo = lhi + 8192;                   // 8192 shorts (lo of -2e)
    float* len = (float*)(lhi + 16384);        // 512 f32

    const int w = threadIdx.x >> 6, l = threadIdx.x & 63;
    const int g = l >> 4, c = l & 15;
    const int half = blockIdx.x & 1;
    const int rowbase = (blockIdx.x >> 1) * 256 + w * 32;

    // A fragments: rows (l&15), k-slots 8g..8g+7 per ktile, split hi/lo
    short8 ahi[2][2], alo[2][2];
#pragma unroll
    for (int mt = 0; mt < 2; ++mt) {
        const float* xr = in + (size_t)(rowbase + mt * 16 + c) * DIM;
#pragma unroll
        for (int kt = 0; kt < 2; ++kt) {
            float4v x0 = *(const float4v*)(xr + kt * 32 + 8 * g);
            float4v x1 = *(const float4v*)(xr + kt * 32 + 8 * g + 4);
            float a[8] = {x0[0], x0[1], x0[2], x0[3], x1[0], x1[1], x1[2], x1[3]};
            short8 h, lo8;
#pragma unroll
            for (int j = 0; j < 8; ++j) {
                unsigned short hb = bf16_rne(a[j]);
                float fhi = __uint_as_float((unsigned)hb << 16);
                h[j]   = (short)hb;
                lo8[j] = (short)bf16_rne(a[j] - fhi);
            }
            ahi[mt][kt] = h;
            alo[mt][kt] = lo8;
        }
    }

    float bst[2][4][2];
#pragma unroll
    for (int mt = 0; mt < 2; ++mt)
#pragma unroll
        for (int j = 0; j < 4; ++j) {
            bst[mt][j][0] = 3.4e38f; bst[mt][j][1] = 3.4e38f;
        }

    for (int qq = 0; qq < 2; ++qq) {
        const int q = half * 2 + qq;           // global quarter
        __syncthreads();                       // prior quarter's reads done
        const int4* src = (const int4*)(wsf + WS_FRAG) + q * 2048;
        int4* dst = (int4*)lhi;
#pragma unroll
        for (int i = 0; i < 4; ++i) dst[i * 512 + threadIdx.x] = src[i * 512 + threadIdx.x];
        if (qq == 0) len[threadIdx.x] = wsf[WS_ENORM + threadIdx.x];
        __syncthreads();

        // this quarter's 8 ||e||^2 values for my code column c
        float en_r[8];
#pragma unroll
        for (int t = 0; t < 8; ++t) en_r[t] = len[q * 128 + t * 16 + c];

#pragma unroll
        for (int t = 0; t < 8; ++t) {
            short8 bh0 = *(const short8*)(lhi + (t * 2 + 0) * 512 + l * 8);
            short8 bh1 = *(const short8*)(lhi + (t * 2 + 1) * 512 + l * 8);
            short8 bl0 = *(const short8*)(llo + (t * 2 + 0) * 512 + l * 8);
            short8 bl1 = *(const short8*)(llo + (t * 2 + 1) * 512 + l * 8);
            float en = en_r[t];
            float4v acc0 = {en, en, en, en};   // d = ||e||^2 - 2 x.e via MFMA
            float4v acc1 = {en, en, en, en};
            acc0 = __builtin_amdgcn_mfma_f32_16x16x32_bf16(ahi[0][0], bh0, acc0, 0, 0, 0);
            acc1 = __builtin_amdgcn_mfma_f32_16x16x32_bf16(ahi[1][0], bh0, acc1, 0, 0, 0);
            acc0 = __builtin_amdgcn_mfma_f32_16x16x32_bf16(ahi[0][1], bh1, acc0, 0, 0, 0);
            acc1 = __builtin_amdgcn_mfma_f32_16x16x32_bf16(ahi[1][1], bh1, acc1, 0, 0, 0);
            acc0 = __builtin_amdgcn_mfma_f32_16x16x32_bf16(alo[0][0], bh0, acc0, 0, 0, 0);
            acc1 = __builtin_amdgcn_mfma_f32_16x16x32_bf16(alo[1][0], bh0, acc1, 0, 0, 0);
            acc0 = __builtin_amdgcn_mfma_f32_16x16x32_bf16(alo[0][1], bh1, acc0, 0, 0, 0);
            acc1 = __builtin_amdgcn_mfma_f32_16x16x32_bf16(alo[1][1], bh1, acc1, 0, 0, 0);
            acc0 = __builtin_amdgcn_mfma_f32_16x16x32_bf16(ahi[0][0], bl0, acc0, 0, 0, 0);
            acc1 = __builtin_amdgcn_mfma_f32_16x16x32_bf16(ahi[1][0], bl0, acc1, 0, 0, 0);
            acc0 = __builtin_amdgcn_mfma_f32_16x16x32_bf16(ahi[0][1], bl1, acc0, 0, 0, 0);
            acc1 = __builtin_amdgcn_mfma_f32_16x16x32_bf16(ahi[1][1], bl1, acc1, 0, 0, 0);

            unsigned nn = (unsigned)(q * 128 + t * 16 + c) & 0x1FFu;
#pragma unroll
            for (int j = 0; j < 4; ++j) {
                float p0 = __uint_as_float((__float_as_uint(acc0[j]) & 0xFFFFFE00u) | nn);
                INS2(p0, bst[0][j][0], bst[0][j][1]);
                float p1 = __uint_as_float((__float_as_uint(acc1[j]) & 0xFFFFFE00u) | nn);
                INS2(p1, bst[1][j][0], bst[1][j][1]);
            }
        }
    }

    // in-wave merge over the 16 c-lanes; lane c==0 stores its half's 8B pair
#pragma unroll
    for (int mt = 0; mt < 2; ++mt)
#pragma unroll
        for (int j = 0; j < 4; ++j) {
            float c0 = bst[mt][j][0], c1 = bst[mt][j][1];
#pragma unroll
            for (int m = 1; m < 16; m <<= 1) {
                float o0 = __shfl_xor(c0, m, 64);
                float o1 = __shfl_xor(c1, m, 64);
                INS2(o0, c0, c1);
                INS2(o1, c0, c1);
            }
            if (c == 0) {
                int row = rowbase + mt * 16 + 4 * g + j;
                float2 cd; cd.x = c0; cd.y = c1;
                *(float2*)(cand + (size_t)row * 4 + 2 * half) = cd;
            }
        }
}

// ---------------------------------------------------------------------------
// k_rerank: FOUR threads per row (sub = t&3). Merge the two halves' packed
// top-2 (order-exact min/med), fp64 re-rank of 2, Q write, loss, inds, hist.
__global__ __launch_bounds__(1024, 8) void k_rerank(const float* __restrict__ in,
                                                    float* __restrict__ wsf,
                                                    int* __restrict__ wsi,
                                                    float* __restrict__ inds_out,
                                                    float* __restrict__ qout) {
    __shared__ int lh[512];
    __shared__ float lred[16];
    int b = blockIdx.x, t = threadIdx.x;
    if (t < 512) lh[t] = 0;
    __syncthreads();

    int row = b * 256 + (t >> 2);
    int sub = t & 3;
    float4v cd4 = *(const float4v*)(wsf + WS_CAND + (size_t)row * 4);
    // top-2 of union of two sorted pairs (a0<=a1, b0<=b1)
    float a0 = cd4[0], a1 = cd4[1], b0 = cd4[2], b1 = cd4[3];
    float m0 = fminf(a0, b0);
    float m1 = fminf(fmaxf(a0, b0), fminf(a1, b1));
    int i0 = (int)(__float_as_uint(m0) & 0x1FFu);
    int i1 = (int)(__float_as_uint(m1) & 0x1FFu);

    const float4v* in4 = (const float4v*)in;
    const float4v* em4 = (const float4v*)(wsf + WS_EMBT);
    double s0 = 0.0, s1 = 0.0, xn = 0.0;
#pragma unroll 2
    for (int q4 = 0; q4 < 4; ++q4) {
        int idx = q4 * 4 + sub;                // wave insn covers full 64B lines
        float4v xv = in4[(size_t)row * 16 + idx];
        float4v e0 = em4[i0 * 16 + idx];
        float4v e1 = em4[i1 * 16 + idx];
#pragma unroll
        for (int q = 0; q < 4; ++q) {
            double xd = (double)xv[q];
            double a = (double)e0[q]; s0 += a * (a - 2.0 * xd);
            double bb = (double)e1[q]; s1 += bb * (bb - 2.0 * xd);
            xn += xd * xd;
        }
    }
#pragma unroll
    for (int m = 1; m < 4; m <<= 1) {
        s0 += __shfl_xor(s0, m, 64);
        s1 += __shfl_xor(s1, m, 64);
        xn += __shfl_xor(xn, m, 64);
    }
    double sb = s0; int ib = i0;
    if (s1 < sb || (s1 == sb && i1 < ib)) { sb = s1; ib = i1; }

    const float4v* eb = em4 + ib * 16;
    float4v* qp = (float4v*)qout + (size_t)row * 16;
#pragma unroll 2
    for (int q4 = 0; q4 < 4; ++q4) {
        int idx = q4 * 4 + sub;
        qp[idx] = eb[idx];
    }

    float ls = 0.f;
    if (sub == 0) {
        inds_out[row] = (float)ib;
        wsi[WS_INDS + row] = ib;
        atomicAdd(&lh[ib], 1);
        ls = (float)(sb + xn);                 // ||q-x||^2
    }
    for (int off = 32; off; off >>= 1) ls += __shfl_down(ls, off, 64);
    if ((t & 63) == 0) lred[t >> 6] = ls;
    __syncthreads();
    if (t == 0) {
        float s = 0.f;
        for (int i = 0; i < 16; ++i) s += lred[i];
        atomicAdd(&wsf[WS_LOSS], s);
    }
    // hist -> HIST2T[code][block] (transposed: scan1 reads coalesced)
    if (t < 512) wsi[WS_HIST2 + t * 512 + b] = lh[t];
}

// ---------------------------------------------------------------------------
// scan1: per-code exclusive scan over 512 block-partials (coalesced reads);
// totals -> HIST/COUNTSF. grid = 512 codes.
__global__ __launch_bounds__(512) void k_scan1(int* __restrict__ wsi,
                                               float* __restrict__ wsf) {
    __shared__ int s[512];
    int e = blockIdx.x, p = threadIdx.x;
    int v = wsi[WS_HIST2 + e * 512 + p];
    s[p] = v;
    __syncthreads();
    for (int off = 1; off < 512; off <<= 1) {
        int a = (p >= off) ? s[p - off] : 0;
        __syncthreads();
        s[p] += a;
        __syncthreads();
    }
    wsi[WS_HIST2 + e * 512 + p] = s[p] - v;
    if (p == 511) {
        wsi[WS_HIST + e] = s[511];
        wsf[WS_COUNTSF + e] = (float)s[511];
    }
}

// ---------------------------------------------------------------------------
// scan2: exclusive scan of per-code totals -> bucket starts. 1 block.
__global__ __launch_bounds__(512) void k_scan2(int* __restrict__ wsi) {
    __shared__ int s[NE];
    int t = threadIdx.x;
    int v = wsi[WS_HIST + t];
    s[t] = v;
    __syncthreads();
    for (int off = 1; off < NE; off <<= 1) {
        int a = (t >= off) ? s[t - off] : 0;
        __syncthreads();
        s[t] += a;
        __syncthreads();
    }
    wsi[WS_START + t] = s[t] - v;
}

// ---------------------------------------------------------------------------
// scatter: atomic-free globally; LDS local rank + scanned (code,block) offset.
__global__ __launch_bounds__(256) void k_scatter(int* __restrict__ wsi) {
    __shared__ int lc[NE];
    int b = blockIdx.x, t = threadIdx.x;
    lc[t] = 0; lc[t + 256] = 0;
    __syncthreads();
    int row = b * 256 + t;
    int ind = wsi[WS_INDS + row];
    int lr = atomicAdd(&lc[ind], 1);
    int pos = wsi[WS_START + ind] + wsi[WS_HIST2 + ind * 512 + b] + lr;
    wsi[WS_SORT + pos] = row;
}

// ---------------------------------------------------------------------------
// sum: skew-immune; wave owns 32 contiguous sorted positions, shfl broadcast,
// flush on (wave-uniform) code change. grid = 1024 x 256.
__global__ __launch_bounds__(256) void k_sum(const float* __restrict__ in,
                                             const int* __restrict__ wsi,
                                             float* __restrict__ wsf) {
    float* __restrict__ esum = wsf + WS_ESUM;
    int wv = threadIdx.x >> 6, lane = threadIdx.x & 63;
    int base = (blockIdx.x * 4 + wv) * 32;
    int rid = 0, cod = 0;
    if (lane < 32) {
        rid = wsi[WS_SORT + base + lane];
        cod = wsi[WS_INDS + rid];
    }
    float acc = 0.f;
    int cur = __shfl(cod, 0, 64);
#pragma unroll 8
    for (int j = 0; j < 32; ++j) {
        int cj = __shfl(cod, j, 64);
        int rj = __shfl(rid, j, 64);
        if (cj != cur) {
            atomicAdd(&esum[cur * DIM + lane], acc);
            acc = 0.f;
            cur = cj;
        }
        acc += in[(size_t)rj * DIM + lane];
    }
    atomicAdd(&esum[cur * DIM + lane], acc);
}

// ---------------------------------------------------------------------------
// finalize: EMA buffers + normalized codebook + loss scale. One block.
__global__ __launch_bounds__(512) void k_final(const float* __restrict__ wsf,
                                               const float* __restrict__ cs_in,
                                               const float* __restrict__ eavg_in,
                                               float* __restrict__ out) {
    __shared__ float sred[512];
    int t = threadIdx.x;
    float c = 0.99f * cs_in[t] + 0.01f * wsf[WS_COUNTSF + t];
    out[OFF_NCS + t] = c;
    sred[t] = c;
    __syncthreads();
    for (int s = 256; s; s >>= 1) {
        if (t < s) sred[t] += sred[t + s];
        __syncthreads();
    }
    float n = sred[0];
    float csv = (c + 1e-5f) / (n + NE * 1e-5f) * n;
    for (int i = t; i < 32768; i += 512) {               // i & 511 == t, d = i>>9
        float nea = 0.99f * eavg_in[i] + 0.01f * wsf[WS_ESUM + t * DIM + (i >> 9)];
        out[OFF_NEA + i]  = nea;
        out[OFF_NEMB + i] = nea / csv;
    }
    if (t == 0) out[OFF_LOSS] = wsf[WS_LOSS] * (1.25f / 8388608.0f);
}

// ---------------------------------------------------------------------------
extern "C" void kernel_launch(void* const* d_in, const int* in_sizes, int n_in,
                              void* d_out, int out_size, void* d_ws, size_t ws_size,
                              hipStream_t stream) {
    const float* in    = (const float*)d_in[0];
    const float* embed = (const float*)d_in[1];
    const float* cs    = (const float*)d_in[2];
    const float* eavg  = (const float*)d_in[3];
    float* out = (float*)d_out;
    float* wsf = (float*)d_ws;
    int*   wsi = (int*)d_ws;

    k_init   <<<517, 256, 0, stream>>>(embed, wsf);
    k_scan   <<<1024, 512, 34816, stream>>>(in, wsf, wsf + WS_CAND);
    k_rerank <<<512, 1024, 0, stream>>>(in, wsf, wsi, out + OFF_INDS, out + OFF_Q);
    k_scan1  <<<NE, 512, 0, stream>>>(wsi, wsf);
    k_scan2  <<<1, 512, 0, stream>>>(wsi);
    k_scatter<<<512, 256, 0, stream>>>(wsi);
    k_sum    <<<1024, 256, 0, stream>>>(in, wsi, wsf);
    k_final  <<<1, 512, 0, stream>>>(wsf, cs, eavg, out);
}

// Round 17
// 81.031 us; speedup vs baseline: 4.2181x; 1.3876x over previous
//
#include <hip/hip_runtime.h>

#define NE    512
#define DIM   64
#define NROWS 131072            // 32*64*64
#define QELEMS (NROWS * DIM)    // 8388608

// ---- output layout (flat f32, reference return order) ----
#define OFF_Q     0
#define OFF_LOSS  8388608
#define OFF_INDS  8388609
#define OFF_NEMB  8519681       // OFF_INDS + 131072
#define OFF_NCS   8552449       // OFF_NEMB + 32768
#define OFF_NEA   8552961       // OFF_NCS  + 512

// ---- workspace layout (float-unit offsets; some regions int/ushort) ----
#define WS_EMBT    0            // [512][64] f32 transposed codebook (e-major)
#define WS_ENORM   32768        // [512] f32 ||e||^2
#define WS_ESUM    33280        // [512][64] f32 segment sums (atomic flush)
#define WS_COUNTSF 66048        // [512] f32 counts
#define WS_LOSS    66560        // [1] f32
#define WS_FRAG    66564        // [4 quarters][hi 8192 | lo 8192] ushort of -2e
#define WS_CAND    99332        // [131072][2] f32 packed top-2 candidates
#define WS_INDS    361476       // [131072] int row -> code
#define WS_SORT    492548       // [131072] int sorted row ids
#define WS_HIST    623620       // [512] int per-code totals
#define WS_HIST2   624644       // [512 codes][512 blocks] int partials (transposed)

typedef __attribute__((ext_vector_type(8))) short short8;
typedef __attribute__((ext_vector_type(4))) float float4v;

__device__ inline unsigned short bf16_rne(float v) {
    unsigned u = __float_as_uint(v);
    u += 0x7fff + ((u >> 16) & 1);
    return (unsigned short)(u >> 16);
}

// insert candidate p into ascending best-2 (b0<=b1): 2 VALU ops
#define INS2(p, b0, b1)                              \
    do {                                             \
        float _p = (p);                              \
        b1 = __builtin_amdgcn_fmed3f(_p, b0, b1);    \
        b0 = fminf(_p, b0);                          \
    } while (0)

// ---------------------------------------------------------------------------
// init: embT + enorm, zero esum/counts/loss, build quarter-major bf16 frags
// of -2*e (so MFMA accumulates the distance directly). grid = 517 x 256.
__global__ __launch_bounds__(256) void k_init(const float* __restrict__ embed,
                                              float* __restrict__ wsf) {
    int tid = blockIdx.x * 256 + threadIdx.x;
    if (tid < 32768) {
        int e = tid >> 6, d = tid & 63;
        wsf[WS_EMBT + tid] = embed[d * NE + e];          // embT[e][d]
    } else if (tid < 33280) {
        int e = tid - 32768;
        float s = 0.f;
        for (int d = 0; d < DIM; ++d) {
            float v = embed[d * NE + e];
            s = fmaf(v, v, s);
        }
        wsf[WS_ENORM + e] = s;
    } else if (tid < 66561) {
        wsf[tid] = 0.f;                                  // ESUM + COUNTSF + LOSS
    } else if (tid >= 66564 && tid < 66564 + 65536) {
        // frag entry ft: q=quarter, part=hi/lo, s=[t8][kt][l][j]; value -2e
        int ft = tid - 66564;
        int q  = ft >> 14;
        int part = (ft >> 13) & 1;
        int s  = ft & 8191;
        int j  = s & 7;
        int l  = (s >> 3) & 63;
        int kt = (s >> 9) & 1;
        int t8 = s >> 10;                                // 0..7
        int k  = kt * 32 + 8 * (l >> 4) + j;
        int n  = q * 128 + t8 * 16 + (l & 15);
        float v = -2.0f * embed[k * NE + n];
        unsigned short hi = bf16_rne(v);
        unsigned short o;
        if (part == 0) o = hi;
        else {
            float fhi = __uint_as_float((unsigned)hi << 16);
            o = bf16_rne(v - fhi);
        }
        ((unsigned short*)(wsf + WS_FRAG))[ft] = o;
    }
}

// ---------------------------------------------------------------------------
// k_scan: R13-identical. 512-thr blocks (8 waves x 32 rows), grid 512, 34KB
// quarter-staged LDS (2 blocks/CU). Distance folded into MFMA.
__global__ __launch_bounds__(512, 2) void k_scan(const float* __restrict__ in,
                                                 const float* __restrict__ wsf,
                                                 float* __restrict__ cand) {
    extern __shared__ char smem[];
    short* lhi = (short*)smem;                 // 8192 shorts (hi of -2e)
    short* llo = lhi + 8192;                   // 8192 shorts (lo of -2e)
    float* len = (float*)(lhi + 16384);        // 512 f32

    const int w = threadIdx.x >> 6, l = threadIdx.x & 63;
    const int g = l >> 4, c = l & 15;
    const int rowbase = blockIdx.x * 256 + w * 32;

    // A fragments: rows (l&15), k-slots 8g..8g+7 per ktile, split hi/lo
    short8 ahi[2][2], alo[2][2];
#pragma unroll
    for (int mt = 0; mt < 2; ++mt) {
        const float* xr = in + (size_t)(rowbase + mt * 16 + c) * DIM;
#pragma unroll
        for (int kt = 0; kt < 2; ++kt) {
            float4v x0 = *(const float4v*)(xr + kt * 32 + 8 * g);
            float4v x1 = *(const float4v*)(xr + kt * 32 + 8 * g + 4);
            float a[8] = {x0[0], x0[1], x0[2], x0[3], x1[0], x1[1], x1[2], x1[3]};
            short8 h, lo8;
#pragma unroll
            for (int j = 0; j < 8; ++j) {
                unsigned short hb = bf16_rne(a[j]);
                float fhi = __uint_as_float((unsigned)hb << 16);
                h[j]   = (short)hb;
                lo8[j] = (short)bf16_rne(a[j] - fhi);
            }
            ahi[mt][kt] = h;
            alo[mt][kt] = lo8;
        }
    }

    float bst[2][4][2];
#pragma unroll
    for (int mt = 0; mt < 2; ++mt)
#pragma unroll
        for (int j = 0; j < 4; ++j) {
            bst[mt][j][0] = 3.4e38f; bst[mt][j][1] = 3.4e38f;
        }

    for (int q = 0; q < 4; ++q) {
        __syncthreads();                       // prior quarter's reads done
        const int4* src = (const int4*)(wsf + WS_FRAG) + q * 2048;
        int4* dst = (int4*)lhi;
#pragma unroll
        for (int i = 0; i < 4; ++i) dst[i * 512 + threadIdx.x] = src[i * 512 + threadIdx.x];
        if (q == 0) len[threadIdx.x] = wsf[WS_ENORM + threadIdx.x];
        __syncthreads();

        // this quarter's 8 ||e||^2 values for my code column c
        float en_r[8];
#pragma unroll
        for (int t = 0; t < 8; ++t) en_r[t] = len[q * 128 + t * 16 + c];

#pragma unroll
        for (int t = 0; t < 8; ++t) {
            short8 bh0 = *(const short8*)(lhi + (t * 2 + 0) * 512 + l * 8);
            short8 bh1 = *(const short8*)(lhi + (t * 2 + 1) * 512 + l * 8);
            short8 bl0 = *(const short8*)(llo + (t * 2 + 0) * 512 + l * 8);
            short8 bl1 = *(const short8*)(llo + (t * 2 + 1) * 512 + l * 8);
            float en = en_r[t];
            float4v acc0 = {en, en, en, en};   // d = ||e||^2 - 2 x.e via MFMA
            float4v acc1 = {en, en, en, en};
            acc0 = __builtin_amdgcn_mfma_f32_16x16x32_bf16(ahi[0][0], bh0, acc0, 0, 0, 0);
            acc1 = __builtin_amdgcn_mfma_f32_16x16x32_bf16(ahi[1][0], bh0, acc1, 0, 0, 0);
            acc0 = __builtin_amdgcn_mfma_f32_16x16x32_bf16(ahi[0][1], bh1, acc0, 0, 0, 0);
            acc1 = __builtin_amdgcn_mfma_f32_16x16x32_bf16(ahi[1][1], bh1, acc1, 0, 0, 0);
            acc0 = __builtin_amdgcn_mfma_f32_16x16x32_bf16(alo[0][0], bh0, acc0, 0, 0, 0);
            acc1 = __builtin_amdgcn_mfma_f32_16x16x32_bf16(alo[1][0], bh0, acc1, 0, 0, 0);
            acc0 = __builtin_amdgcn_mfma_f32_16x16x32_bf16(alo[0][1], bh1, acc0, 0, 0, 0);
            acc1 = __builtin_amdgcn_mfma_f32_16x16x32_bf16(alo[1][1], bh1, acc1, 0, 0, 0);
            acc0 = __builtin_amdgcn_mfma_f32_16x16x32_bf16(ahi[0][0], bl0, acc0, 0, 0, 0);
            acc1 = __builtin_amdgcn_mfma_f32_16x16x32_bf16(ahi[1][0], bl0, acc1, 0, 0, 0);
            acc0 = __builtin_amdgcn_mfma_f32_16x16x32_bf16(ahi[0][1], bl1, acc0, 0, 0, 0);
            acc1 = __builtin_amdgcn_mfma_f32_16x16x32_bf16(ahi[1][1], bl1, acc1, 0, 0, 0);

            unsigned nn = (unsigned)(q * 128 + t * 16 + c) & 0x1FFu;
#pragma unroll
            for (int j = 0; j < 4; ++j) {
                float p0 = __uint_as_float((__float_as_uint(acc0[j]) & 0xFFFFFE00u) | nn);
                INS2(p0, bst[0][j][0], bst[0][j][1]);
                float p1 = __uint_as_float((__float_as_uint(acc1[j]) & 0xFFFFFE00u) | nn);
                INS2(p1, bst[1][j][0], bst[1][j][1]);
            }
        }
    }

    // in-wave merge over the 16 c-lanes; lane c==0 stores 8B of candidates
#pragma unroll
    for (int mt = 0; mt < 2; ++mt)
#pragma unroll
        for (int j = 0; j < 4; ++j) {
            float c0 = bst[mt][j][0], c1 = bst[mt][j][1];
#pragma unroll
            for (int m = 1; m < 16; m <<= 1) {
                float o0 = __shfl_xor(c0, m, 64);
                float o1 = __shfl_xor(c1, m, 64);
                INS2(o0, c0, c1);
                INS2(o1, c0, c1);
            }
            if (c == 0) {
                int row = rowbase + mt * 16 + 4 * g + j;
                float2 cd; cd.x = c0; cd.y = c1;
                *(float2*)(cand + (size_t)row * 2) = cd;
            }
        }
}

// ---------------------------------------------------------------------------
// k_rerank: FOUR threads per row (sub = t&3). fp64 re-rank of 2 candidates,
// Q write (reload embT[ib]), loss, inds, per-block hist. block 1024, grid 512.
__global__ __launch_bounds__(1024, 8) void k_rerank(const float* __restrict__ in,
                                                    float* __restrict__ wsf,
                                                    int* __restrict__ wsi,
                                                    float* __restrict__ inds_out,
                                                    float* __restrict__ qout) {
    __shared__ int lh[512];
    __shared__ float lred[16];
    int b = blockIdx.x, t = threadIdx.x;
    if (t < 512) lh[t] = 0;
    __syncthreads();

    int row = b * 256 + (t >> 2);
    int sub = t & 3;
    float2 cd = *(const float2*)(wsf + WS_CAND + (size_t)row * 2);
    int i0 = (int)(__float_as_uint(cd.x) & 0x1FFu);
    int i1 = (int)(__float_as_uint(cd.y) & 0x1FFu);

    const float4v* in4 = (const float4v*)in;
    const float4v* em4 = (const float4v*)(wsf + WS_EMBT);
    double s0 = 0.0, s1 = 0.0, xn = 0.0;
#pragma unroll 2
    for (int q4 = 0; q4 < 4; ++q4) {
        int idx = q4 * 4 + sub;                // wave insn covers full 64B lines
        float4v xv = in4[(size_t)row * 16 + idx];
        float4v e0 = em4[i0 * 16 + idx];
        float4v e1 = em4[i1 * 16 + idx];
#pragma unroll
        for (int q = 0; q < 4; ++q) {
            double xd = (double)xv[q];
            double a = (double)e0[q]; s0 += a * (a - 2.0 * xd);
            double bb = (double)e1[q]; s1 += bb * (bb - 2.0 * xd);
            xn += xd * xd;
        }
    }
#pragma unroll
    for (int m = 1; m < 4; m <<= 1) {
        s0 += __shfl_xor(s0, m, 64);
        s1 += __shfl_xor(s1, m, 64);
        xn += __shfl_xor(xn, m, 64);
    }
    double sb = s0; int ib = i0;
    if (s1 < sb || (s1 == sb && i1 < ib)) { sb = s1; ib = i1; }

    const float4v* eb = em4 + ib * 16;
    float4v* qp = (float4v*)qout + (size_t)row * 16;
#pragma unroll 2
    for (int q4 = 0; q4 < 4; ++q4) {
        int idx = q4 * 4 + sub;
        qp[idx] = eb[idx];
    }

    float ls = 0.f;
    if (sub == 0) {
        inds_out[row] = (float)ib;
        wsi[WS_INDS + row] = ib;
        atomicAdd(&lh[ib], 1);
        ls = (float)(sb + xn);                 // ||q-x||^2
    }
    for (int off = 32; off; off >>= 1) ls += __shfl_down(ls, off, 64);
    if ((t & 63) == 0) lred[t >> 6] = ls;
    __syncthreads();
    if (t == 0) {
        float s = 0.f;
        for (int i = 0; i < 16; ++i) s += lred[i];
        atomicAdd(&wsf[WS_LOSS], s);
    }
    // hist -> HIST2T[code][block] (transposed: scan1 reads coalesced)
    if (t < 512) wsi[WS_HIST2 + t * 512 + b] = lh[t];
}

// ---------------------------------------------------------------------------
// scan1: per-code exclusive scan over 512 block-partials via WAVE-SCAN
// (shfl_up intra-wave + 8-partial cross-wave; 1 barrier). grid = 512 codes.
__global__ __launch_bounds__(512) void k_scan1(int* __restrict__ wsi,
                                               float* __restrict__ wsf) {
    __shared__ int wtot[8];
    int e = blockIdx.x, p = threadIdx.x;
    int lane = p & 63, wid = p >> 6;
    int v = wsi[WS_HIST2 + e * 512 + p];
    int x = v;
#pragma unroll
    for (int off = 1; off < 64; off <<= 1) {
        int o = __shfl_up(x, off, 64);
        if (lane >= off) x += o;
    }
    if (lane == 63) wtot[wid] = x;
    __syncthreads();
    int base = 0;
#pragma unroll
    for (int i = 0; i < 8; ++i) base += (i < wid) ? wtot[i] : 0;
    wsi[WS_HIST2 + e * 512 + p] = base + x - v;       // exclusive over blocks
    if (p == 511) {
        int tot = base + x;
        wsi[WS_HIST + e] = tot;
        wsf[WS_COUNTSF + e] = (float)tot;
    }
}

// ---------------------------------------------------------------------------
// scatter: folds the cross-code prefix (old scan2) into each block's LDS,
// then atomic-free global scatter via LDS local rank. grid = 512 x 256.
__global__ __launch_bounds__(256) void k_scatter(int* __restrict__ wsi) {
    __shared__ int s[512], horig[512], lc[512];
    int b = blockIdx.x, t = threadIdx.x;
    int h0 = wsi[WS_HIST + t];
    int h1 = wsi[WS_HIST + t + 256];
    s[t] = h0; s[t + 256] = h1;
    horig[t] = h0; horig[t + 256] = h1;
    lc[t] = 0; lc[t + 256] = 0;
    __syncthreads();
    for (int off = 1; off < 512; off <<= 1) {
        int a0 = (t >= off) ? s[t - off] : 0;
        int a1 = (t + 256 >= off) ? s[t + 256 - off] : 0;
        __syncthreads();
        s[t] += a0; s[t + 256] += a1;
        __syncthreads();
    }
    int row = b * 256 + t;
    int ind = wsi[WS_INDS + row];
    int lr = atomicAdd(&lc[ind], 1);
    int start = s[ind] - horig[ind];                   // exclusive prefix
    int pos = start + wsi[WS_HIST2 + ind * 512 + b] + lr;
    wsi[WS_SORT + pos] = row;
}

// ---------------------------------------------------------------------------
// sum: skew-immune; wave owns 32 contiguous sorted positions, shfl broadcast,
// flush on (wave-uniform) code change. grid = 1024 x 256.
__global__ __launch_bounds__(256) void k_sum(const float* __restrict__ in,
                                             const int* __restrict__ wsi,
                                             float* __restrict__ wsf) {
    float* __restrict__ esum = wsf + WS_ESUM;
    int wv = threadIdx.x >> 6, lane = threadIdx.x & 63;
    int base = (blockIdx.x * 4 + wv) * 32;
    int rid = 0, cod = 0;
    if (lane < 32) {
        rid = wsi[WS_SORT + base + lane];
        cod = wsi[WS_INDS + rid];
    }
    float acc = 0.f;
    int cur = __shfl(cod, 0, 64);
#pragma unroll 8
    for (int j = 0; j < 32; ++j) {
        int cj = __shfl(cod, j, 64);
        int rj = __shfl(rid, j, 64);
        if (cj != cur) {
            atomicAdd(&esum[cur * DIM + lane], acc);
            acc = 0.f;
            cur = cj;
        }
        acc += in[(size_t)rj * DIM + lane];
    }
    atomicAdd(&esum[cur * DIM + lane], acc);
}

// ---------------------------------------------------------------------------
// finalize: WIDENED to 64 blocks x 512 thr; one output element per thread,
// per-block redundant n-reduction. EMA buffers + codebook + loss.
__global__ __launch_bounds__(512) void k_final(const float* __restrict__ wsf,
                                               const float* __restrict__ cs_in,
                                               const float* __restrict__ eavg_in,
                                               float* __restrict__ out) {
    __shared__ float sred[512];
    int b = blockIdx.x, t = threadIdx.x;
    float cme = 0.99f * cs_in[t] + 0.01f * wsf[WS_COUNTSF + t];
    sred[t] = cme;
    __syncthreads();
    for (int s = 256; s; s >>= 1) {
        if (t < s) sred[t] += sred[t + s];
        __syncthreads();
    }
    float n = sred[0];

    int i = b * 512 + t;                       // 64*512 = 32768 outputs
    int e = i & 511, d = i >> 9;
    float ce = 0.99f * cs_in[e] + 0.01f * wsf[WS_COUNTSF + e];
    float csv = (ce + 1e-5f) / (n + NE * 1e-5f) * n;
    float nea = 0.99f * eavg_in[i] + 0.01f * wsf[WS_ESUM + e * DIM + d];
    out[OFF_NEA + i]  = nea;
    out[OFF_NEMB + i] = nea / csv;
    if (b == 0) out[OFF_NCS + t] = cme;
    if (i == 0) out[OFF_LOSS] = wsf[WS_LOSS] * (1.25f / 8388608.0f);
}

// ---------------------------------------------------------------------------
extern "C" void kernel_launch(void* const* d_in, const int* in_sizes, int n_in,
                              void* d_out, int out_size, void* d_ws, size_t ws_size,
                              hipStream_t stream) {
    const float* in    = (const float*)d_in[0];
    const float* embed = (const float*)d_in[1];
    const float* cs    = (const float*)d_in[2];
    const float* eavg  = (const float*)d_in[3];
    float* out = (float*)d_out;
    float* wsf = (float*)d_ws;
    int*   wsi = (int*)d_ws;

    k_init   <<<517, 256, 0, stream>>>(embed, wsf);
    k_scan   <<<512, 512, 34816, stream>>>(in, wsf, wsf + WS_CAND);
    k_rerank <<<512, 1024, 0, stream>>>(in, wsf, wsi, out + OFF_INDS, out + OFF_Q);
    k_scan1  <<<NE, 512, 0, stream>>>(wsi, wsf);
    k_scatter<<<512, 256, 0, stream>>>(wsi);
    k_sum    <<<1024, 256, 0, stream>>>(in, wsi, wsf);
    k_final  <<<64, 512, 0, stream>>>(wsf, cs, eavg, out);
}

// Round 18
// 74.227 us; speedup vs baseline: 4.6048x; 1.0917x over previous
//
#include <hip/hip_runtime.h>

#define NE    512
#define DIM   64
#define NROWS 131072            // 32*64*64
#define QELEMS (NROWS * DIM)    // 8388608

// ---- output layout (flat f32, reference return order) ----
#define OFF_Q     0
#define OFF_LOSS  8388608
#define OFF_INDS  8388609
#define OFF_NEMB  8519681       // OFF_INDS + 131072
#define OFF_NCS   8552449       // OFF_NEMB + 32768
#define OFF_NEA   8552961       // OFF_NCS  + 512

// ---- workspace layout (float-unit offsets; some regions int/ushort) ----
#define WS_EMBT    0            // [512][64] f32 transposed codebook (e-major)
#define WS_ENORM   32768        // [512] f32 ||e||^2
#define WS_ESUM    33280        // [512][64] f32 segment sums (atomic flush)
#define WS_COUNTSF 66048        // [512] f32 counts
#define WS_LOSS    66560        // [1] f32
#define WS_FRAG    66564        // [4 quarters][8192] ushort bf16(-2e) (single prec)
#define WS_CAND    99332        // [131072][2] f32 packed top-2 candidates
#define WS_INDS    361476       // [131072] int row -> code
#define WS_SORT    492548       // [131072] int sorted row ids
#define WS_HIST    623620       // [512] int per-code totals
#define WS_HIST2   624644       // [512 codes][512 blocks] int partials (transposed)

typedef __attribute__((ext_vector_type(8))) short short8;
typedef __attribute__((ext_vector_type(4))) float float4v;

__device__ inline unsigned short bf16_rne(float v) {
    unsigned u = __float_as_uint(v);
    u += 0x7fff + ((u >> 16) & 1);
    return (unsigned short)(u >> 16);
}

// insert candidate p into ascending best-2 (b0<=b1): 2 VALU ops
#define INS2(p, b0, b1)                              \
    do {                                             \
        float _p = (p);                              \
        b1 = __builtin_amdgcn_fmed3f(_p, b0, b1);    \
        b0 = fminf(_p, b0);                          \
    } while (0)

// ---------------------------------------------------------------------------
// init: embT + enorm, zero esum/counts/loss, build quarter-major SINGLE-bf16
// frags of -2*e (scan only needs top-2 membership; fp64 rerank is exact).
// grid = 389 x 256.
__global__ __launch_bounds__(256) void k_init(const float* __restrict__ embed,
                                              float* __restrict__ wsf) {
    int tid = blockIdx.x * 256 + threadIdx.x;
    if (tid < 32768) {
        int e = tid >> 6, d = tid & 63;
        wsf[WS_EMBT + tid] = embed[d * NE + e];          // embT[e][d]
    } else if (tid < 33280) {
        int e = tid - 32768;
        float s = 0.f;
        for (int d = 0; d < DIM; ++d) {
            float v = embed[d * NE + e];
            s = fmaf(v, v, s);
        }
        wsf[WS_ENORM + e] = s;
    } else if (tid < 66561) {
        wsf[tid] = 0.f;                                  // ESUM + COUNTSF + LOSS
    } else if (tid >= 66564 && tid < 66564 + 32768) {
        // frag entry ft: q=quarter, s=[t8][kt][l][j]; value bf16(-2e)
        int ft = tid - 66564;
        int q  = ft >> 13;
        int s  = ft & 8191;
        int j  = s & 7;
        int l  = (s >> 3) & 63;
        int kt = (s >> 9) & 1;
        int t8 = s >> 10;                                // 0..7
        int k  = kt * 32 + 8 * (l >> 4) + j;
        int n  = q * 128 + t8 * 16 + (l & 15);
        ((unsigned short*)(wsf + WS_FRAG))[ft] = bf16_rne(-2.0f * embed[k * NE + n]);
    }
}

// ---------------------------------------------------------------------------
// k_scan: R13 geometry (512 thr, grid 512, quarter-staged, (512,2)) but
// SINGLE-bf16 path: 16KB LDS/quarter, 2 ds_reads + 4 MFMAs per t-iter
// (halved staging/LDS/MFMA vs split). Distance folded into MFMA acc init.
__global__ __launch_bounds__(512, 2) void k_scan(const float* __restrict__ in,
                                                 const float* __restrict__ wsf,
                                                 float* __restrict__ cand) {
    extern __shared__ char smem[];
    short* lhi = (short*)smem;                 // 8192 shorts (bf16 of -2e)
    float* len = (float*)(lhi + 8192);         // 512 f32

    const int w = threadIdx.x >> 6, l = threadIdx.x & 63;
    const int g = l >> 4, c = l & 15;
    const int rowbase = blockIdx.x * 256 + w * 32;

    // A fragments: rows (l&15), k-slots 8g..8g+7 per ktile, single bf16
    short8 ahi[2][2];
#pragma unroll
    for (int mt = 0; mt < 2; ++mt) {
        const float* xr = in + (size_t)(rowbase + mt * 16 + c) * DIM;
#pragma unroll
        for (int kt = 0; kt < 2; ++kt) {
            float4v x0 = *(const float4v*)(xr + kt * 32 + 8 * g);
            float4v x1 = *(const float4v*)(xr + kt * 32 + 8 * g + 4);
            float a[8] = {x0[0], x0[1], x0[2], x0[3], x1[0], x1[1], x1[2], x1[3]};
            short8 h;
#pragma unroll
            for (int j = 0; j < 8; ++j) h[j] = (short)bf16_rne(a[j]);
            ahi[mt][kt] = h;
        }
    }

    float bst[2][4][2];
#pragma unroll
    for (int mt = 0; mt < 2; ++mt)
#pragma unroll
        for (int j = 0; j < 4; ++j) {
            bst[mt][j][0] = 3.4e38f; bst[mt][j][1] = 3.4e38f;
        }

    for (int q = 0; q < 4; ++q) {
        __syncthreads();                       // prior quarter's reads done
        const int4* src = (const int4*)(wsf + WS_FRAG) + q * 1024;
        int4* dst = (int4*)lhi;
#pragma unroll
        for (int i = 0; i < 2; ++i) dst[i * 512 + threadIdx.x] = src[i * 512 + threadIdx.x];
        if (q == 0) len[threadIdx.x] = wsf[WS_ENORM + threadIdx.x];
        __syncthreads();

        // this quarter's 8 ||e||^2 values for my code column c
        float en_r[8];
#pragma unroll
        for (int t = 0; t < 8; ++t) en_r[t] = len[q * 128 + t * 16 + c];

#pragma unroll
        for (int t = 0; t < 8; ++t) {
            short8 bh0 = *(const short8*)(lhi + (t * 2 + 0) * 512 + l * 8);
            short8 bh1 = *(const short8*)(lhi + (t * 2 + 1) * 512 + l * 8);
            float en = en_r[t];
            float4v acc0 = {en, en, en, en};   // d = ||e||^2 - 2 x.e via MFMA
            float4v acc1 = {en, en, en, en};
            acc0 = __builtin_amdgcn_mfma_f32_16x16x32_bf16(ahi[0][0], bh0, acc0, 0, 0, 0);
            acc1 = __builtin_amdgcn_mfma_f32_16x16x32_bf16(ahi[1][0], bh0, acc1, 0, 0, 0);
            acc0 = __builtin_amdgcn_mfma_f32_16x16x32_bf16(ahi[0][1], bh1, acc0, 0, 0, 0);
            acc1 = __builtin_amdgcn_mfma_f32_16x16x32_bf16(ahi[1][1], bh1, acc1, 0, 0, 0);

            unsigned nn = (unsigned)(q * 128 + t * 16 + c) & 0x1FFu;
#pragma unroll
            for (int j = 0; j < 4; ++j) {
                float p0 = __uint_as_float((__float_as_uint(acc0[j]) & 0xFFFFFE00u) | nn);
                INS2(p0, bst[0][j][0], bst[0][j][1]);
                float p1 = __uint_as_float((__float_as_uint(acc1[j]) & 0xFFFFFE00u) | nn);
                INS2(p1, bst[1][j][0], bst[1][j][1]);
            }
        }
    }

    // in-wave merge over the 16 c-lanes; lane c==0 stores 8B of candidates
#pragma unroll
    for (int mt = 0; mt < 2; ++mt)
#pragma unroll
        for (int j = 0; j < 4; ++j) {
            float c0 = bst[mt][j][0], c1 = bst[mt][j][1];
#pragma unroll
            for (int m = 1; m < 16; m <<= 1) {
                float o0 = __shfl_xor(c0, m, 64);
                float o1 = __shfl_xor(c1, m, 64);
                INS2(o0, c0, c1);
                INS2(o1, c0, c1);
            }
            if (c == 0) {
                int row = rowbase + mt * 16 + 4 * g + j;
                float2 cd; cd.x = c0; cd.y = c1;
                *(float2*)(cand + (size_t)row * 2) = cd;
            }
        }
}

// ---------------------------------------------------------------------------
// k_rerank: FOUR threads per row (sub = t&3). fp64 re-rank of 2 candidates,
// Q write (reload embT[ib]), loss, inds, per-block hist. block 1024, grid 512.
__global__ __launch_bounds__(1024, 8) void k_rerank(const float* __restrict__ in,
                                                    float* __restrict__ wsf,
                                                    int* __restrict__ wsi,
                                                    float* __restrict__ inds_out,
                                                    float* __restrict__ qout) {
    __shared__ int lh[512];
    __shared__ float lred[16];
    int b = blockIdx.x, t = threadIdx.x;
    if (t < 512) lh[t] = 0;
    __syncthreads();

    int row = b * 256 + (t >> 2);
    int sub = t & 3;
    float2 cd = *(const float2*)(wsf + WS_CAND + (size_t)row * 2);
    int i0 = (int)(__float_as_uint(cd.x) & 0x1FFu);
    int i1 = (int)(__float_as_uint(cd.y) & 0x1FFu);

    const float4v* in4 = (const float4v*)in;
    const float4v* em4 = (const float4v*)(wsf + WS_EMBT);
    double s0 = 0.0, s1 = 0.0, xn = 0.0;
#pragma unroll 2
    for (int q4 = 0; q4 < 4; ++q4) {
        int idx = q4 * 4 + sub;                // wave insn covers full 64B lines
        float4v xv = in4[(size_t)row * 16 + idx];
        float4v e0 = em4[i0 * 16 + idx];
        float4v e1 = em4[i1 * 16 + idx];
#pragma unroll
        for (int q = 0; q < 4; ++q) {
            double xd = (double)xv[q];
            double a = (double)e0[q]; s0 += a * (a - 2.0 * xd);
            double bb = (double)e1[q]; s1 += bb * (bb - 2.0 * xd);
            xn += xd * xd;
        }
    }
#pragma unroll
    for (int m = 1; m < 4; m <<= 1) {
        s0 += __shfl_xor(s0, m, 64);
        s1 += __shfl_xor(s1, m, 64);
        xn += __shfl_xor(xn, m, 64);
    }
    double sb = s0; int ib = i0;
    if (s1 < sb || (s1 == sb && i1 < ib)) { sb = s1; ib = i1; }

    const float4v* eb = em4 + ib * 16;
    float4v* qp = (float4v*)qout + (size_t)row * 16;
#pragma unroll 2
    for (int q4 = 0; q4 < 4; ++q4) {
        int idx = q4 * 4 + sub;
        qp[idx] = eb[idx];
    }

    float ls = 0.f;
    if (sub == 0) {
        inds_out[row] = (float)ib;
        wsi[WS_INDS + row] = ib;
        atomicAdd(&lh[ib], 1);
        ls = (float)(sb + xn);                 // ||q-x||^2
    }
    for (int off = 32; off; off >>= 1) ls += __shfl_down(ls, off, 64);
    if ((t & 63) == 0) lred[t >> 6] = ls;
    __syncthreads();
    if (t == 0) {
        float s = 0.f;
        for (int i = 0; i < 16; ++i) s += lred[i];
        atomicAdd(&wsf[WS_LOSS], s);
    }
    // hist -> HIST2T[code][block] (transposed: scan1 reads coalesced)
    if (t < 512) wsi[WS_HIST2 + t * 512 + b] = lh[t];
}

// ---------------------------------------------------------------------------
// scan1: per-code exclusive scan over 512 block-partials via WAVE-SCAN
// (shfl_up intra-wave + 8-partial cross-wave; 1 barrier). grid = 512 codes.
__global__ __launch_bounds__(512) void k_scan1(int* __restrict__ wsi,
                                               float* __restrict__ wsf) {
    __shared__ int wtot[8];
    int e = blockIdx.x, p = threadIdx.x;
    int lane = p & 63, wid = p >> 6;
    int v = wsi[WS_HIST2 + e * 512 + p];
    int x = v;
#pragma unroll
    for (int off = 1; off < 64; off <<= 1) {
        int o = __shfl_up(x, off, 64);
        if (lane >= off) x += o;
    }
    if (lane == 63) wtot[wid] = x;
    __syncthreads();
    int base = 0;
#pragma unroll
    for (int i = 0; i < 8; ++i) base += (i < wid) ? wtot[i] : 0;
    wsi[WS_HIST2 + e * 512 + p] = base + x - v;       // exclusive over blocks
    if (p == 511) {
        int tot = base + x;
        wsi[WS_HIST + e] = tot;
        wsf[WS_COUNTSF + e] = (float)tot;
    }
}

// ---------------------------------------------------------------------------
// scatter: folds the cross-code prefix into each block's LDS, then
// atomic-free global scatter via LDS local rank. grid = 512 x 256.
__global__ __launch_bounds__(256) void k_scatter(int* __restrict__ wsi) {
    __shared__ int s[512], horig[512], lc[512];
    int b = blockIdx.x, t = threadIdx.x;
    int h0 = wsi[WS_HIST + t];
    int h1 = wsi[WS_HIST + t + 256];
    s[t] = h0; s[t + 256] = h1;
    horig[t] = h0; horig[t + 256] = h1;
    lc[t] = 0; lc[t + 256] = 0;
    __syncthreads();
    for (int off = 1; off < 512; off <<= 1) {
        int a0 = (t >= off) ? s[t - off] : 0;
        int a1 = (t + 256 >= off) ? s[t + 256 - off] : 0;
        __syncthreads();
        s[t] += a0; s[t + 256] += a1;
        __syncthreads();
    }
    int row = b * 256 + t;
    int ind = wsi[WS_INDS + row];
    int lr = atomicAdd(&lc[ind], 1);
    int start = s[ind] - horig[ind];                   // exclusive prefix
    int pos = start + wsi[WS_HIST2 + ind * 512 + b] + lr;
    wsi[WS_SORT + pos] = row;
}

// ---------------------------------------------------------------------------
// sum: skew-immune; wave owns 32 contiguous sorted positions, shfl broadcast,
// flush on (wave-uniform) code change. grid = 1024 x 256.
__global__ __launch_bounds__(256) void k_sum(const float* __restrict__ in,
                                             const int* __restrict__ wsi,
                                             float* __restrict__ wsf) {
    float* __restrict__ esum = wsf + WS_ESUM;
    int wv = threadIdx.x >> 6, lane = threadIdx.x & 63;
    int base = (blockIdx.x * 4 + wv) * 32;
    int rid = 0, cod = 0;
    if (lane < 32) {
        rid = wsi[WS_SORT + base + lane];
        cod = wsi[WS_INDS + rid];
    }
    float acc = 0.f;
    int cur = __shfl(cod, 0, 64);
#pragma unroll 8
    for (int j = 0; j < 32; ++j) {
        int cj = __shfl(cod, j, 64);
        int rj = __shfl(rid, j, 64);
        if (cj != cur) {
            atomicAdd(&esum[cur * DIM + lane], acc);
            acc = 0.f;
            cur = cj;
        }
        acc += in[(size_t)rj * DIM + lane];
    }
    atomicAdd(&esum[cur * DIM + lane], acc);
}

// ---------------------------------------------------------------------------
// finalize: 64 blocks x 512 thr; one output element per thread,
// per-block redundant n-reduction. EMA buffers + codebook + loss.
__global__ __launch_bounds__(512) void k_final(const float* __restrict__ wsf,
                                               const float* __restrict__ cs_in,
                                               const float* __restrict__ eavg_in,
                                               float* __restrict__ out) {
    __shared__ float sred[512];
    int b = blockIdx.x, t = threadIdx.x;
    float cme = 0.99f * cs_in[t] + 0.01f * wsf[WS_COUNTSF + t];
    sred[t] = cme;
    __syncthreads();
    for (int s = 256; s; s >>= 1) {
        if (t < s) sred[t] += sred[t + s];
        __syncthreads();
    }
    float n = sred[0];

    int i = b * 512 + t;                       // 64*512 = 32768 outputs
    int e = i & 511, d = i >> 9;
    float ce = 0.99f * cs_in[e] + 0.01f * wsf[WS_COUNTSF + e];
    float csv = (ce + 1e-5f) / (n + NE * 1e-5f) * n;
    float nea = 0.99f * eavg_in[i] + 0.01f * wsf[WS_ESUM + e * DIM + d];
    out[OFF_NEA + i]  = nea;
    out[OFF_NEMB + i] = nea / csv;
    if (b == 0) out[OFF_NCS + t] = cme;
    if (i == 0) out[OFF_LOSS] = wsf[WS_LOSS] * (1.25f / 8388608.0f);
}

// ---------------------------------------------------------------------------
extern "C" void kernel_launch(void* const* d_in, const int* in_sizes, int n_in,
                              void* d_out, int out_size, void* d_ws, size_t ws_size,
                              hipStream_t stream) {
    const float* in    = (const float*)d_in[0];
    const float* embed = (const float*)d_in[1];
    const float* cs    = (const float*)d_in[2];
    const float* eavg  = (const float*)d_in[3];
    float* out = (float*)d_out;
    float* wsf = (float*)d_ws;
    int*   wsi = (int*)d_ws;

    k_init   <<<389, 256, 0, stream>>>(embed, wsf);
    k_scan   <<<512, 512, 18432, stream>>>(in, wsf, wsf + WS_CAND);
    k_rerank <<<512, 1024, 0, stream>>>(in, wsf, wsi, out + OFF_INDS, out + OFF_Q);
    k_scan1  <<<NE, 512, 0, stream>>>(wsi, wsf);
    k_scatter<<<512, 256, 0, stream>>>(wsi);
    k_sum    <<<1024, 256, 0, stream>>>(in, wsi, wsf);
    k_final  <<<64, 512, 0, stream>>>(wsf, cs, eavg, out);
}